// Round 6
// baseline (341.993 us; speedup 1.0000x reference)
//
#include <hip/hip_runtime.h>

// SIREN forward, MFMA, round 6: round-5 contiguous epilogue + NT stores.
//
// Ladder so far: 1526 (f32 spill) -> 473 (MFMA chain) -> 472 (128B-line NT,
// no effect) -> 326 us (1KB-contiguous cached stores: FETCH 1.43->0.73 GB).
// Remaining 733 MB fetch ~= 1.37x output => still store-miss line fills
// (TCC allocates sectors on the first 128B write request). Round 4 had NT
// but scattered stores; round 5 contiguity but no NT. This round: both.
// Single variable vs round 5: __builtin_nontemporal_store on the final
// 1KB-contiguous f32x4 stores.

typedef _Float16 half8 __attribute__((ext_vector_type(8)));
typedef float f32x4 __attribute__((ext_vector_type(4)));

#define OMEGA 5.0f

__global__ __launch_bounds__(256, 2) void siren_mfma_kernel(
    const float* __restrict__ coords,
    const float* __restrict__ W0, const float* __restrict__ b0,
    const float* __restrict__ W1, const float* __restrict__ b1,
    const float* __restrict__ W2, const float* __restrict__ b2,
    const float* __restrict__ W3, const float* __restrict__ b3,
    const float* __restrict__ W4, const float* __restrict__ b4,
    float* __restrict__ out, int n)
{
    // Pre-gathered A-fragment tables: [kblock][mtile][lane] -> 8 f16 (16 B).
    __shared__ half8 AT[3][2][4][64];    // hidden layers W1..W3: 24 KB
    __shared__ half8 AT4[2][8][64];      // W4: 16 KB
    __shared__ float4 w0tab[64];         // {5*W0[n][0], 5*W0[n][1], 5*b0[n], 0}
    __shared__ __align__(16) float btab[3][64];   // 5*b1..b3
    __shared__ __align__(16) float b4tab[128];    // 5*b4
    // Per-wave full output slab: 16 points x 128 cols f32 (8 KB/wave, 32 KB).
    // float4-chunk XOR swizzle (chunk ^= row&7): balanced banks on both the
    // MFMA-side b128 writes and the store-side b128 reads (0 conflicts, r5).
    __shared__ float stage[4][16][128];

    const int tid  = threadIdx.x;
    const int lane = tid & 63;
    const int g    = lane >> 4;        // lane group 0..3
    const int w    = tid >> 6;         // wave in block

    // ---------------- prep: build fragment tables ----------------
    {
        const float* Wp[3] = {W1, W2, W3};
        #pragma unroll
        for (int L = 0; L < 3; ++L) {
            #pragma unroll
            for (int c = 0; c < 2; ++c) {
                int chunk = w + 4 * c;               // 0..7 = b*4 + mt
                int b  = chunk >> 2, mt = chunk & 3;
                const float* src = Wp[L] + (16 * mt + (lane & 15)) * 64 + 32 * b + 4 * g;
                float4 wa = *(const float4*)(src);
                float4 wb = *(const float4*)(src + 16);
                half8 h;
                h[0] = (_Float16)(OMEGA * wa.x); h[1] = (_Float16)(OMEGA * wa.y);
                h[2] = (_Float16)(OMEGA * wa.z); h[3] = (_Float16)(OMEGA * wa.w);
                h[4] = (_Float16)(OMEGA * wb.x); h[5] = (_Float16)(OMEGA * wb.y);
                h[6] = (_Float16)(OMEGA * wb.z); h[7] = (_Float16)(OMEGA * wb.w);
                AT[L][b][mt][lane] = h;
            }
        }
        #pragma unroll
        for (int c = 0; c < 4; ++c) {
            int chunk = w + 4 * c;                   // 0..15 = b*8 + mt
            int b  = chunk >> 3, mt = chunk & 7;
            const float* src = W4 + (16 * mt + (lane & 15)) * 64 + 32 * b + 4 * g;
            float4 wa = *(const float4*)(src);
            float4 wb = *(const float4*)(src + 16);
            half8 h;
            h[0] = (_Float16)(OMEGA * wa.x); h[1] = (_Float16)(OMEGA * wa.y);
            h[2] = (_Float16)(OMEGA * wa.z); h[3] = (_Float16)(OMEGA * wa.w);
            h[4] = (_Float16)(OMEGA * wb.x); h[5] = (_Float16)(OMEGA * wb.y);
            h[6] = (_Float16)(OMEGA * wb.z); h[7] = (_Float16)(OMEGA * wb.w);
            AT4[b][mt][lane] = h;
        }
        if (tid < 64) {
            w0tab[tid] = make_float4(OMEGA * W0[2 * tid], OMEGA * W0[2 * tid + 1],
                                     OMEGA * b0[tid], 0.f);
            btab[0][tid] = OMEGA * b1[tid];
            btab[1][tid] = OMEGA * b2[tid];
            btab[2][tid] = OMEGA * b3[tid];
        }
        if (tid < 128) b4tab[tid] = OMEGA * b4[tid];
    }
    __syncthreads();

    // ---------------- main loop: one wave = 16 points per batch ----------------
    const int p   = lane & 15;                // point-in-batch (= MFMA column)
    const int sr  = lane >> 5;                // store-side row parity (0/1)
    const int sc  = lane & 31;                // store-side float4 chunk 0..31
    const int nb  = (n + 15) >> 4;
    const int wv  = blockIdx.x * 4 + w;
    const int nw  = gridDim.x * 4;

    for (int batch = wv; batch < nb; batch += nw) {
        int point = batch * 16 + p;
        int pt    = point < n ? point : n - 1;
        float2 c2 = *(const float2*)(coords + 2ull * (unsigned)pt);

        // Layer 0 (fp32 VALU): lane computes Z0[n][p] for n = 16t+4g+r,
        // landing directly in B-fragment slots: zb[t>>1][4*(t&1)+r].
        half8 zb[2];
        #pragma unroll
        for (int t = 0; t < 4; ++t) {
            #pragma unroll
            for (int r = 0; r < 4; ++r) {
                float4 ww = w0tab[16 * t + 4 * g + r];
                float z = __sinf(fmaf(c2.x, ww.x, fmaf(c2.y, ww.y, ww.z)));
                zb[t >> 1][4 * (t & 1) + r] = (_Float16)z;
            }
        }

        // Hidden layers 1..3
        #pragma unroll
        for (int L = 0; L < 3; ++L) {
            f32x4 acc[4];
            #pragma unroll
            for (int t = 0; t < 4; ++t) {
                float4 bv = *(const float4*)&btab[L][16 * t + 4 * g];
                acc[t][0] = bv.x; acc[t][1] = bv.y; acc[t][2] = bv.z; acc[t][3] = bv.w;
            }
            #pragma unroll
            for (int b = 0; b < 2; ++b) {
                #pragma unroll
                for (int mt = 0; mt < 4; ++mt) {
                    acc[mt] = __builtin_amdgcn_mfma_f32_16x16x32_f16(
                        AT[L][b][mt][lane], zb[b], acc[mt], 0, 0, 0);
                }
            }
            // activation + repack: D-regs -> next B-frags, all in-lane
            half8 zn[2];
            #pragma unroll
            for (int t = 0; t < 4; ++t) {
                #pragma unroll
                for (int r = 0; r < 4; ++r) {
                    zn[t >> 1][4 * (t & 1) + r] = (_Float16)__sinf(acc[t][r]);
                }
            }
            zb[0] = zn[0]; zb[1] = zn[1];
        }

        // Output layer: 64 -> 128, all 8 mt-tiles into the per-wave LDS slab
        // (chunk-XOR swizzle), then 8 fully-contiguous 1 KB NT stores.
        #pragma unroll
        for (int mt = 0; mt < 8; ++mt) {
            float4 bv = *(const float4*)&b4tab[16 * mt + 4 * g];
            f32x4 a4;
            a4[0] = bv.x; a4[1] = bv.y; a4[2] = bv.z; a4[3] = bv.w;
            a4 = __builtin_amdgcn_mfma_f32_16x16x32_f16(AT4[0][mt][lane], zb[0], a4, 0, 0, 0);
            a4 = __builtin_amdgcn_mfma_f32_16x16x32_f16(AT4[1][mt][lane], zb[1], a4, 0, 0, 0);
            f32x4 o;
            o[0] = __sinf(a4[0]); o[1] = __sinf(a4[1]);
            o[2] = __sinf(a4[2]); o[3] = __sinf(a4[3]);
            int chunk = (4 * mt + g) ^ (p & 7);      // float4-chunk swizzle
            *(f32x4*)&stage[w][p][4 * chunk] = o;
        }
        // Store: instruction i writes point rows 2i (lanes 0-31) and 2i+1
        // (lanes 32-63) -- 1 KB contiguous per instruction, 8 KB back-to-back.
        // NT: no-allocate -> full-line writes skip the read-for-ownership.
        const float* sbase = &stage[w][0][0];
        #pragma unroll
        for (int i = 0; i < 8; ++i) {
            int row = 2 * i + sr;
            int cs  = sc ^ (row & 7);
            f32x4 o4 = *(const f32x4*)(sbase + 128 * row + 4 * cs);
            int pointp = batch * 16 + row;
            if (pointp < n) {
                __builtin_nontemporal_store(o4, (f32x4*)(out + (size_t)pointp * 128 + 4 * sc));
            }
        }
    }
}

extern "C" void kernel_launch(void* const* d_in, const int* in_sizes, int n_in,
                              void* d_out, int out_size, void* d_ws, size_t ws_size,
                              hipStream_t stream) {
    const float* coords = (const float*)d_in[0];
    const float* W0 = (const float*)d_in[1];
    const float* b0 = (const float*)d_in[2];
    const float* W1 = (const float*)d_in[3];
    const float* b1 = (const float*)d_in[4];
    const float* W2 = (const float*)d_in[5];
    const float* b2 = (const float*)d_in[6];
    const float* W3 = (const float*)d_in[7];
    const float* b3 = (const float*)d_in[8];
    const float* W4 = (const float*)d_in[9];
    const float* b4 = (const float*)d_in[10];
    float* out = (float*)d_out;

    int n = in_sizes[0] / 2;  // coords is (N, 2)
    int nb = (n + 15) / 16;
    int blocks = 512;         // 2 blocks/CU (74.5 KB LDS), 4 waves each
    int maxb = (nb + 3) / 4;
    if (blocks > maxb) blocks = maxb;
    hipLaunchKernelGGL(siren_mfma_kernel, dim3(blocks), dim3(256), 0, stream,
                       coords, W0, b0, W1, b1, W2, b2, W3, b3, W4, b4, out, n);
}

// Round 7
// 122.461 us; speedup vs baseline: 2.7927x; 2.7927x over previous
//
#include <hip/hip_runtime.h>

// SIREN forward, MFMA, round 7: round-5 epilogue + system-scope (sc0 sc1)
// streaming stores.
//
// Ladder: 1526 (f32 spill) -> 473 (MFMA chain) -> 326 us (1KB-contiguous
// cached stores; FETCH 1.43 GB -> 733 MB). Round 6 proved `nt` alone does
// NOT suppress the L2 fetch-on-write-miss (FETCH unchanged, dur +5%).
// Model: TCC read-fills every missed store line; the only lever left is
// scope. sc0+sc1 (system scope) stores must bypass the non-coherent per-XCD
// L2 -> no ownership -> no RFO fetch. Single variable vs r5: the final
// store instruction is inline-asm global_store_dwordx4 sc0 sc1 nt.

typedef _Float16 half8 __attribute__((ext_vector_type(8)));
typedef float f32x4 __attribute__((ext_vector_type(4)));

#define OMEGA 5.0f

__global__ __launch_bounds__(256, 2) void siren_mfma_kernel(
    const float* __restrict__ coords,
    const float* __restrict__ W0, const float* __restrict__ b0,
    const float* __restrict__ W1, const float* __restrict__ b1,
    const float* __restrict__ W2, const float* __restrict__ b2,
    const float* __restrict__ W3, const float* __restrict__ b3,
    const float* __restrict__ W4, const float* __restrict__ b4,
    float* __restrict__ out, int n)
{
    // Pre-gathered A-fragment tables: [kblock][mtile][lane] -> 8 f16 (16 B).
    __shared__ half8 AT[3][2][4][64];    // hidden layers W1..W3: 24 KB
    __shared__ half8 AT4[2][8][64];      // W4: 16 KB
    __shared__ float4 w0tab[64];         // {5*W0[n][0], 5*W0[n][1], 5*b0[n], 0}
    __shared__ __align__(16) float btab[3][64];   // 5*b1..b3
    __shared__ __align__(16) float b4tab[128];    // 5*b4
    // Per-wave full output slab: 16 points x 128 cols f32 (8 KB/wave, 32 KB).
    // float4-chunk XOR swizzle (chunk ^= row&7): 0 bank conflicts (r5 PMC).
    __shared__ float stage[4][16][128];

    const int tid  = threadIdx.x;
    const int lane = tid & 63;
    const int g    = lane >> 4;        // lane group 0..3
    const int w    = tid >> 6;         // wave in block

    // ---------------- prep: build fragment tables ----------------
    {
        const float* Wp[3] = {W1, W2, W3};
        #pragma unroll
        for (int L = 0; L < 3; ++L) {
            #pragma unroll
            for (int c = 0; c < 2; ++c) {
                int chunk = w + 4 * c;               // 0..7 = b*4 + mt
                int b  = chunk >> 2, mt = chunk & 3;
                const float* src = Wp[L] + (16 * mt + (lane & 15)) * 64 + 32 * b + 4 * g;
                float4 wa = *(const float4*)(src);
                float4 wb = *(const float4*)(src + 16);
                half8 h;
                h[0] = (_Float16)(OMEGA * wa.x); h[1] = (_Float16)(OMEGA * wa.y);
                h[2] = (_Float16)(OMEGA * wa.z); h[3] = (_Float16)(OMEGA * wa.w);
                h[4] = (_Float16)(OMEGA * wb.x); h[5] = (_Float16)(OMEGA * wb.y);
                h[6] = (_Float16)(OMEGA * wb.z); h[7] = (_Float16)(OMEGA * wb.w);
                AT[L][b][mt][lane] = h;
            }
        }
        #pragma unroll
        for (int c = 0; c < 4; ++c) {
            int chunk = w + 4 * c;                   // 0..15 = b*8 + mt
            int b  = chunk >> 3, mt = chunk & 7;
            const float* src = W4 + (16 * mt + (lane & 15)) * 64 + 32 * b + 4 * g;
            float4 wa = *(const float4*)(src);
            float4 wb = *(const float4*)(src + 16);
            half8 h;
            h[0] = (_Float16)(OMEGA * wa.x); h[1] = (_Float16)(OMEGA * wa.y);
            h[2] = (_Float16)(OMEGA * wa.z); h[3] = (_Float16)(OMEGA * wa.w);
            h[4] = (_Float16)(OMEGA * wb.x); h[5] = (_Float16)(OMEGA * wb.y);
            h[6] = (_Float16)(OMEGA * wb.z); h[7] = (_Float16)(OMEGA * wb.w);
            AT4[b][mt][lane] = h;
        }
        if (tid < 64) {
            w0tab[tid] = make_float4(OMEGA * W0[2 * tid], OMEGA * W0[2 * tid + 1],
                                     OMEGA * b0[tid], 0.f);
            btab[0][tid] = OMEGA * b1[tid];
            btab[1][tid] = OMEGA * b2[tid];
            btab[2][tid] = OMEGA * b3[tid];
        }
        if (tid < 128) b4tab[tid] = OMEGA * b4[tid];
    }
    __syncthreads();

    // ---------------- main loop: one wave = 16 points per batch ----------------
    const int p   = lane & 15;                // point-in-batch (= MFMA column)
    const int sr  = lane >> 5;                // store-side row parity (0/1)
    const int sc  = lane & 31;                // store-side float4 chunk 0..31
    const int nb  = (n + 15) >> 4;
    const int wv  = blockIdx.x * 4 + w;
    const int nw  = gridDim.x * 4;

    for (int batch = wv; batch < nb; batch += nw) {
        int point = batch * 16 + p;
        int pt    = point < n ? point : n - 1;
        float2 c2 = *(const float2*)(coords + 2ull * (unsigned)pt);

        // Layer 0 (fp32 VALU): lane computes Z0[n][p] for n = 16t+4g+r,
        // landing directly in B-fragment slots: zb[t>>1][4*(t&1)+r].
        half8 zb[2];
        #pragma unroll
        for (int t = 0; t < 4; ++t) {
            #pragma unroll
            for (int r = 0; r < 4; ++r) {
                float4 ww = w0tab[16 * t + 4 * g + r];
                float z = __sinf(fmaf(c2.x, ww.x, fmaf(c2.y, ww.y, ww.z)));
                zb[t >> 1][4 * (t & 1) + r] = (_Float16)z;
            }
        }

        // Hidden layers 1..3
        #pragma unroll
        for (int L = 0; L < 3; ++L) {
            f32x4 acc[4];
            #pragma unroll
            for (int t = 0; t < 4; ++t) {
                float4 bv = *(const float4*)&btab[L][16 * t + 4 * g];
                acc[t][0] = bv.x; acc[t][1] = bv.y; acc[t][2] = bv.z; acc[t][3] = bv.w;
            }
            #pragma unroll
            for (int b = 0; b < 2; ++b) {
                #pragma unroll
                for (int mt = 0; mt < 4; ++mt) {
                    acc[mt] = __builtin_amdgcn_mfma_f32_16x16x32_f16(
                        AT[L][b][mt][lane], zb[b], acc[mt], 0, 0, 0);
                }
            }
            // activation + repack: D-regs -> next B-frags, all in-lane
            half8 zn[2];
            #pragma unroll
            for (int t = 0; t < 4; ++t) {
                #pragma unroll
                for (int r = 0; r < 4; ++r) {
                    zn[t >> 1][4 * (t & 1) + r] = (_Float16)__sinf(acc[t][r]);
                }
            }
            zb[0] = zn[0]; zb[1] = zn[1];
        }

        // Output layer: 64 -> 128, all 8 mt-tiles into the per-wave LDS slab
        // (chunk-XOR swizzle), then 8 fully-contiguous 1 KB stores.
        #pragma unroll
        for (int mt = 0; mt < 8; ++mt) {
            float4 bv = *(const float4*)&b4tab[16 * mt + 4 * g];
            f32x4 a4;
            a4[0] = bv.x; a4[1] = bv.y; a4[2] = bv.z; a4[3] = bv.w;
            a4 = __builtin_amdgcn_mfma_f32_16x16x32_f16(AT4[0][mt][lane], zb[0], a4, 0, 0, 0);
            a4 = __builtin_amdgcn_mfma_f32_16x16x32_f16(AT4[1][mt][lane], zb[1], a4, 0, 0, 0);
            f32x4 o;
            o[0] = __sinf(a4[0]); o[1] = __sinf(a4[1]);
            o[2] = __sinf(a4[2]); o[3] = __sinf(a4[3]);
            int chunk = (4 * mt + g) ^ (p & 7);      // float4-chunk swizzle
            *(f32x4*)&stage[w][p][4 * chunk] = o;
        }
        // Store: instruction i writes point rows 2i (lanes 0-31) and 2i+1
        // (lanes 32-63) -- 1 KB contiguous per instruction.
        // sc0 sc1 nt: system-scope streaming store -> bypass per-XCD L2,
        // no line ownership, no read-for-ownership fill (the r7 hypothesis).
        const float* sbase = &stage[w][0][0];
        #pragma unroll
        for (int i = 0; i < 8; ++i) {
            int row = 2 * i + sr;
            int cs  = sc ^ (row & 7);
            f32x4 o4 = *(const f32x4*)(sbase + 128 * row + 4 * cs);
            int pointp = batch * 16 + row;
            if (pointp < n) {
                float* gp = out + (size_t)pointp * 128 + 4 * sc;
                asm volatile("global_store_dwordx4 %0, %1, off sc0 sc1 nt"
                             :: "v"(gp), "v"(o4) : "memory");
            }
        }
    }
}

extern "C" void kernel_launch(void* const* d_in, const int* in_sizes, int n_in,
                              void* d_out, int out_size, void* d_ws, size_t ws_size,
                              hipStream_t stream) {
    const float* coords = (const float*)d_in[0];
    const float* W0 = (const float*)d_in[1];
    const float* b0 = (const float*)d_in[2];
    const float* W1 = (const float*)d_in[3];
    const float* b1 = (const float*)d_in[4];
    const float* W2 = (const float*)d_in[5];
    const float* b2 = (const float*)d_in[6];
    const float* W3 = (const float*)d_in[7];
    const float* b3 = (const float*)d_in[8];
    const float* W4 = (const float*)d_in[9];
    const float* b4 = (const float*)d_in[10];
    float* out = (float*)d_out;

    int n = in_sizes[0] / 2;  // coords is (N, 2)
    int nb = (n + 15) / 16;
    int blocks = 512;         // 2 blocks/CU (74.5 KB LDS), 4 waves each
    int maxb = (nb + 3) / 4;
    if (blocks > maxb) blocks = maxb;
    hipLaunchKernelGGL(siren_mfma_kernel, dim3(blocks), dim3(256), 0, stream,
                       coords, W0, b0, W1, b1, W2, b2, W3, b3, W4, b4, out, n);
}